// Round 1
// baseline (3513.487 us; speedup 1.0000x reference)
//
#include <hip/hip_runtime.h>
#include <math.h>

#define NQ   2048
#define NS   65536
#define FDIM 512
#define KSEL 16
#define QT   64     // query tile per block
#define NT   64     // support sub-tile
#define KB   32     // K block
#define ALD  68     // padded LDS leading dim for A/B tiles (floats)
#define SLD  69     // padded score leading dim
#define TLD  17     // padded top-k leading dim

// ---------------- norms: q2[2048], s2[65536] ----------------
__global__ void knn_norms(const float* __restrict__ q, const float* __restrict__ s,
                          float* __restrict__ q2, float* __restrict__ s2) {
  int wid  = (int)blockIdx.x * 4 + ((int)threadIdx.x >> 6);
  int lane = threadIdx.x & 63;
  if (wid >= NQ + NS) return;
  const float* src = (wid < NQ) ? (q + (size_t)wid * FDIM)
                                : (s + (size_t)(wid - NQ) * FDIM);
  float acc = 0.f;
#pragma unroll
  for (int j = 0; j < FDIM / 64; ++j) {
    float v = src[lane + 64 * j];
    acc = fmaf(v, v, acc);
  }
#pragma unroll
  for (int off = 32; off; off >>= 1) acc += __shfl_xor(acc, off, 64);
  if (lane == 0) {
    if (wid < NQ) q2[wid] = acc;
    else          s2[wid - NQ] = acc;
  }
}

// ---------------- phase 1: fused GEMM + per-chunk top-16 ----------------
// block: 256 threads. computes 64 queries x (NS/NCHUNKT) supports,
// keeps running sorted top-16 per query in LDS, writes candidates to ws.
template <int NCHUNKT>
__global__ __launch_bounds__(256) void knn_phase1(
    const float* __restrict__ query, const float* __restrict__ support,
    const float* __restrict__ q2g, const float* __restrict__ s2g,
    float* __restrict__ cand_d, int* __restrict__ cand_i) {
  constexpr int CHUNKSZ = NS / NCHUNKT;

  __shared__ __align__(16) float AsT[KB][ALD];  // [k][query]
  __shared__ __align__(16) float BsT[KB][ALD];  // [k][support]
  __shared__ float score[QT][SLD];
  __shared__ float topd[QT][TLD];
  __shared__ int   topi[QT][TLD];
  __shared__ float q2s[QT];
  __shared__ float s2s[NT];

  const int tid = threadIdx.x;
  const int tx  = tid & 15;   // support col group (4 cols)
  const int ty  = tid >> 4;   // query  row group (4 rows)
  const int q0  = (int)blockIdx.x * QT;
  const int chunk = blockIdx.y;

  if (tid < QT) {
    q2s[tid] = q2g[q0 + tid];
#pragma unroll
    for (int j = 0; j < KSEL; ++j) topd[tid][j] = INFINITY;
  }

  for (int st = 0; st < CHUNKSZ / NT; ++st) {
    const int s0 = chunk * CHUNKSZ + st * NT;
    if (tid < NT) s2s[tid] = s2g[s0 + tid];

    float acc[4][4] = {{0.f, 0.f, 0.f, 0.f}};
    for (int kb = 0; kb < FDIM / KB; ++kb) {
      __syncthreads();
      // stage 64x32 A and B tiles, transposed into LDS
#pragma unroll
      for (int h = 0; h < 2; ++h) {
        int f   = tid + h * 256;       // 0..511 -> 64 rows x 8 float4
        int row = f >> 3;
        int kc  = (f & 7) << 2;
        float4 av = *(const float4*)&query[(size_t)(q0 + row) * FDIM + kb * KB + kc];
        AsT[kc + 0][row] = av.x; AsT[kc + 1][row] = av.y;
        AsT[kc + 2][row] = av.z; AsT[kc + 3][row] = av.w;
        float4 bv = *(const float4*)&support[(size_t)(s0 + row) * FDIM + kb * KB + kc];
        BsT[kc + 0][row] = bv.x; BsT[kc + 1][row] = bv.y;
        BsT[kc + 2][row] = bv.z; BsT[kc + 3][row] = bv.w;
      }
      __syncthreads();
#pragma unroll
      for (int kk = 0; kk < KB; ++kk) {
        float4 a = *(const float4*)&AsT[kk][ty * 4];
        float4 b = *(const float4*)&BsT[kk][tx * 4];
        float a4[4] = {a.x, a.y, a.z, a.w};
        float b4[4] = {b.x, b.y, b.z, b.w};
#pragma unroll
        for (int i = 0; i < 4; ++i)
#pragma unroll
          for (int j = 0; j < 4; ++j)
            acc[i][j] = fmaf(a4[i], b4[j], acc[i][j]);
      }
    }
    // d2 = q2 + s2 - 2*dot  -> score tile
#pragma unroll
    for (int i = 0; i < 4; ++i)
#pragma unroll
      for (int j = 0; j < 4; ++j)
        score[ty * 4 + i][tx * 4 + j] =
            q2s[ty * 4 + i] + s2s[tx * 4 + j] - 2.f * acc[i][j];
    __syncthreads();
    // one thread per query row: insertion-scan 64 candidates into sorted top-16
    if (tid < QT) {
      const int row = tid;
      for (int c = 0; c < NT; ++c) {
        float dv = score[row][c];
        if (dv < topd[row][KSEL - 1]) {
          int p = KSEL - 1;
          while (p > 0 && dv < topd[row][p - 1]) {   // strict <: stable ties
            topd[row][p] = topd[row][p - 1];
            topi[row][p] = topi[row][p - 1];
            --p;
          }
          topd[row][p] = dv;
          topi[row][p] = s0 + c;
        }
      }
    }
    __syncthreads();  // protect score/s2s before next sub-tile
  }
  // write 64x16 candidates: layout [q][chunk][16]
  {
    int row = tid >> 2;
    int j0  = (tid & 3) * 4;
    size_t base = ((size_t)(q0 + row) * NCHUNKT + chunk) * KSEL;
#pragma unroll
    for (int j = 0; j < 4; ++j) {
      cand_d[base + j0 + j] = topd[row][j0 + j];
      cand_i[base + j0 + j] = topi[row][j0 + j];
    }
  }
}

// ---------------- phase 2: merge candidates, weights, output ----------------
template <int NCHUNKT>
__global__ __launch_bounds__(64) void knn_phase2(
    const float* __restrict__ cand_d, const int* __restrict__ cand_i,
    float* __restrict__ out) {
  constexpr int NCAND = NCHUNKT * KSEL;    // 512 or 1024
  constexpr int SLOTS = NCAND / 64;        // 8 or 16
  __shared__ float wd[KSEL];
  __shared__ int   wi[KSEL];

  const int q    = blockIdx.x;
  const int lane = threadIdx.x;
  const float* cd = cand_d + (size_t)q * NCAND;
  const int*   ci = cand_i + (size_t)q * NCAND;

  float d[SLOTS]; int idx[SLOTS];
#pragma unroll
  for (int s = 0; s < SLOTS; ++s) {
    d[s]   = cd[lane + 64 * s];
    idx[s] = ci[lane + 64 * s];
  }

  for (int r = 0; r < KSEL; ++r) {
    float bd = INFINITY; int bi = 0x7fffffff;
#pragma unroll
    for (int s = 0; s < SLOTS; ++s) {
      bool better = (d[s] < bd) || (d[s] == bd && idx[s] < bi);
      if (better) { bd = d[s]; bi = idx[s]; }
    }
#pragma unroll
    for (int off = 32; off; off >>= 1) {
      float od = __shfl_xor(bd, off, 64);
      int   oi = __shfl_xor(bi, off, 64);
      if (od < bd || (od == bd && oi < bi)) { bd = od; bi = oi; }
    }
    // owner invalidates (support indices are unique)
#pragma unroll
    for (int s = 0; s < SLOTS; ++s)
      if (idx[s] == bi) { d[s] = INFINITY; idx[s] = 0x7fffffff; }
    if (lane == 0) { wd[r] = bd; wi[r] = bi; }
  }
  __syncthreads();

  float sim = 0.f;
  if (lane < KSEL) {
    float dist = sqrtf(fmaxf(wd[lane], 1e-12f));
    sim = 1.f / (dist + 1e-6f);
  }
  float tot = sim;
#pragma unroll
  for (int off = 8; off; off >>= 1) tot += __shfl_xor(tot, off, 64);
  if (lane < KSEL) {
    out[(size_t)q * KSEL + lane] = (float)wi[lane];                      // indices as f32
    out[(size_t)NQ * KSEL + (size_t)q * KSEL + lane] = sim / tot;        // weights
  }
}

extern "C" void kernel_launch(void* const* d_in, const int* in_sizes, int n_in,
                              void* d_out, int out_size, void* d_ws, size_t ws_size,
                              hipStream_t stream) {
  const float* query   = (const float*)d_in[0];
  const float* support = (const float*)d_in[1];
  float* out = (float*)d_out;

  float* q2     = (float*)d_ws;                // 2048 f
  float* s2     = q2 + NQ;                     // 65536 f
  float* cand_d = s2 + NS;                     // up to 2048*1024 f
  // ws need for NCHUNK=64: (2048 + 65536 + 2*2048*1024)*4 ≈ 17 MB
  size_t need64 = (size_t)(NQ + NS + 2 * NQ * 64 * KSEL) * 4;

  knn_norms<<<(NQ + NS) / 4, 256, 0, stream>>>(query, support, q2, s2);

  if (ws_size >= need64) {
    int* cand_i = (int*)(cand_d + (size_t)NQ * 64 * KSEL);
    dim3 g1(NQ / QT, 64);
    knn_phase1<64><<<g1, 256, 0, stream>>>(query, support, q2, s2, cand_d, cand_i);
    knn_phase2<64><<<NQ, 64, 0, stream>>>(cand_d, cand_i, out);
  } else {
    int* cand_i = (int*)(cand_d + (size_t)NQ * 32 * KSEL);
    dim3 g1(NQ / QT, 32);
    knn_phase1<32><<<g1, 256, 0, stream>>>(query, support, q2, s2, cand_d, cand_i);
    knn_phase2<32><<<NQ, 64, 0, stream>>>(cand_d, cand_i, out);
  }
}

// Round 2
// 2154.794 us; speedup vs baseline: 1.6305x; 1.6305x over previous
//
#include <hip/hip_runtime.h>
#include <math.h>

#define NQ   2048
#define NS   65536
#define FDIM 512
#define KSEL 16
#define LDA  132   // AsT row stride (floats): k-rows x 128 queries, padded
#define LDB  320   // BsT row stride: 16 col-blocks x 20 floats (16 used + 4 pad)
#define LDT  132   // scrT row stride: 64 cols x 128 rows, padded

// ---------------- norms: q2[2048], s2[65536] ----------------
__global__ void knn_norms(const float* __restrict__ q, const float* __restrict__ s,
                          float* __restrict__ q2, float* __restrict__ s2) {
  int wid  = (int)blockIdx.x * 4 + ((int)threadIdx.x >> 6);
  int lane = threadIdx.x & 63;
  if (wid >= NQ + NS) return;
  const float* src = (wid < NQ) ? (q + (size_t)wid * FDIM)
                                : (s + (size_t)(wid - NQ) * FDIM);
  float acc = 0.f;
#pragma unroll
  for (int j = 0; j < FDIM / 256; ++j) {
    float4 v = *(const float4*)&src[(lane + 64 * j) * 4];
    acc = fmaf(v.x, v.x, acc); acc = fmaf(v.y, v.y, acc);
    acc = fmaf(v.z, v.z, acc); acc = fmaf(v.w, v.w, acc);
  }
#pragma unroll
  for (int off = 32; off; off >>= 1) acc += __shfl_xor(acc, off, 64);
  if (lane == 0) {
    if (wid < NQ) q2[wid] = acc;
    else          s2[wid - NQ] = acc;
  }
}

// ---------------- phase 1: fused GEMM + per-thread register top-16 ----------
// 256 threads as (tx=0..15, ty=0..15); micro-tile 8 rows x 16 cols per thread.
// Block tile: 128 queries x 256 supports per sub-tile; CHUNKSZ supports/block.
// Scores e = s2 - 2*dot (q2 added in phase2; per-row constant doesn't affect
// selection). Selection: HALVES threads per row, each keeps sorted top-16 of
// its column stream in registers (ties keep earlier arrival = smaller index).
template <int NCHUNK, int HALVES>
__global__ __launch_bounds__(256, 2) void knn_phase1(
    const float* __restrict__ query, const float* __restrict__ support,
    const float* __restrict__ s2g,
    float* __restrict__ cand_e, int* __restrict__ cand_i) {
  constexpr int CHUNKSZ = NS / NCHUNK;
  constexpr int NST = CHUNKSZ / 256;

  __shared__ __align__(16) float AsT[16][LDA];
  __shared__ __align__(16) float BsT[16 * LDB];
  __shared__ __align__(16) float scrT[64][LDT];
  __shared__ float s2s[256];

  const int tid = threadIdx.x;
  const int tx  = tid & 15;
  const int ty  = tid >> 4;
  const int q0  = (int)blockIdx.x * 128;
  const int chunk = blockIdx.y;

  // persistent per-thread selection list (sorted ascending by e)
  float ld[KSEL]; int li[KSEL];
#pragma unroll
  for (int s = 0; s < KSEL; ++s) { ld[s] = INFINITY; li[s] = 0x7fffffff; }
  const int  srow  = (HALVES == 2) ? (tid >> 1) : tid;
  const int  shalf = (HALVES == 2) ? (tid & 1) : 0;
  const bool scan_active = (HALVES == 2) || (tid < 128);

  for (int st = 0; st < NST; ++st) {
    const int s0 = chunk * CHUNKSZ + st * 256;
    s2s[tid] = s2g[s0 + tid];           // barrier before use comes from k-loop

    float acc[8][16];
#pragma unroll
    for (int i = 0; i < 8; ++i)
#pragma unroll
      for (int j = 0; j < 16; ++j) acc[i][j] = 0.f;

    float4 pa[2], pb[4];
    const int rr = tid >> 2, cq = tid & 3, cc = cq << 2;

    // prefetch kb=0
#pragma unroll
    for (int p = 0; p < 2; ++p)
      pa[p] = *(const float4*)&query[(size_t)(q0 + rr + 64 * p) * FDIM + cc];
#pragma unroll
    for (int p = 0; p < 4; ++p)
      pb[p] = *(const float4*)&support[(size_t)(s0 + rr + 64 * p) * FDIM + cc];

    for (int kb = 0; kb < FDIM / 16; ++kb) {
      __syncthreads();                  // prior reads of AsT/BsT done
      // regs -> LDS (transposed)
#pragma unroll
      for (int p = 0; p < 2; ++p) {
        const int r = rr + 64 * p;
        const float v[4] = {pa[p].x, pa[p].y, pa[p].z, pa[p].w};
#pragma unroll
        for (int j = 0; j < 4; ++j) AsT[cq * 4 + j][r] = v[j];
      }
#pragma unroll
      for (int p = 0; p < 4; ++p) {
        const int r  = rr + 64 * p;
        const int pc = 20 * (r >> 4) + (r & 15);
        const float v[4] = {pb[p].x, pb[p].y, pb[p].z, pb[p].w};
#pragma unroll
        for (int j = 0; j < 4; ++j) BsT[(cq * 4 + j) * LDB + pc] = v[j];
      }
      // prefetch next kb
      if (kb + 1 < FDIM / 16) {
        const int kc = (kb + 1) * 16 + cc;
#pragma unroll
        for (int p = 0; p < 2; ++p)
          pa[p] = *(const float4*)&query[(size_t)(q0 + rr + 64 * p) * FDIM + kc];
#pragma unroll
        for (int p = 0; p < 4; ++p)
          pb[p] = *(const float4*)&support[(size_t)(s0 + rr + 64 * p) * FDIM + kc];
      }
      __syncthreads();                  // tiles ready
#pragma unroll 4
      for (int kk = 0; kk < 16; ++kk) {
        float4 a0 = *(const float4*)&AsT[kk][ty * 8];
        float4 a1 = *(const float4*)&AsT[kk][ty * 8 + 4];
        const float* brow = &BsT[kk * LDB + 20 * tx];
        float4 b0 = *(const float4*)&brow[0];
        float4 b1 = *(const float4*)&brow[4];
        float4 b2 = *(const float4*)&brow[8];
        float4 b3 = *(const float4*)&brow[12];
        const float a[8]  = {a0.x, a0.y, a0.z, a0.w, a1.x, a1.y, a1.z, a1.w};
        const float b[16] = {b0.x, b0.y, b0.z, b0.w, b1.x, b1.y, b1.z, b1.w,
                             b2.x, b2.y, b2.z, b2.w, b3.x, b3.y, b3.z, b3.w};
#pragma unroll
        for (int i = 0; i < 8; ++i)
#pragma unroll
          for (int j = 0; j < 16; ++j)
            acc[i][j] = fmaf(a[i], b[j], acc[i][j]);
      }
    }

    // ---- selection over this 128x256 score tile, 4 slices of 64 cols ----
#pragma unroll 1
    for (int sl = 0; sl < 4; ++sl) {
      __syncthreads();                  // prev scan done; k-loop reads done
      if ((tx >> 2) == sl) {            // 64 writer threads own these 64 cols
        const int csb = (tx & 3) * 16;
#pragma unroll
        for (int j = 0; j < 16; ++j) {
          const float s2v = s2s[tx * 16 + j];
          float4 v0, v1;
          v0.x = fmaf(-2.f, acc[0][j], s2v);
          v0.y = fmaf(-2.f, acc[1][j], s2v);
          v0.z = fmaf(-2.f, acc[2][j], s2v);
          v0.w = fmaf(-2.f, acc[3][j], s2v);
          v1.x = fmaf(-2.f, acc[4][j], s2v);
          v1.y = fmaf(-2.f, acc[5][j], s2v);
          v1.z = fmaf(-2.f, acc[6][j], s2v);
          v1.w = fmaf(-2.f, acc[7][j], s2v);
          *(float4*)&scrT[csb + j][ty * 8]     = v0;
          *(float4*)&scrT[csb + j][ty * 8 + 4] = v1;
        }
      }
      __syncthreads();
      if (scan_active) {
        const int cbase = s0 + sl * 64 + shalf * 32;
        const int ccount = (HALVES == 2) ? 32 : 64;
        const int coff   = (HALVES == 2) ? shalf * 32 : 0;
        for (int c = 0; c < ccount; ++c) {
          const float ev = scrT[coff + c][srow];
          if (ev < ld[KSEL - 1]) {      // rare accept path
            bool lt[KSEL];
#pragma unroll
            for (int s = 0; s < KSEL; ++s) lt[s] = ev < ld[s];
            const int iv = cbase + c;
#pragma unroll
            for (int s = KSEL - 1; s >= 1; --s) {
              ld[s] = lt[s - 1] ? ld[s - 1] : (lt[s] ? ev : ld[s]);
              li[s] = lt[s - 1] ? li[s - 1] : (lt[s] ? iv : li[s]);
            }
            if (lt[0]) { ld[0] = ev; li[0] = iv; }
          }
        }
      }
    }
  }

  // write candidate lists: [q][chunk*(HALVES*16) + shalf*16 + j]
  if (scan_active) {
    const size_t base =
        ((size_t)(q0 + srow) * NCHUNK + chunk) * (HALVES * KSEL) + shalf * KSEL;
#pragma unroll
    for (int j = 0; j < KSEL; ++j) {
      cand_e[base + j] = ld[j];
      cand_i[base + j] = li[j];
    }
  }
}

// ---------------- phase 2: merge candidates, weights, output ----------------
template <int NCAND>
__global__ __launch_bounds__(64) void knn_phase2(
    const float* __restrict__ cand_e, const int* __restrict__ cand_i,
    const float* __restrict__ q2g, float* __restrict__ out) {
  constexpr int SLOTS = NCAND / 64;
  __shared__ float wd[KSEL];
  __shared__ int   wi[KSEL];

  const int q    = blockIdx.x;
  const int lane = threadIdx.x;
  const float q2 = q2g[q];
  const float* ce = cand_e + (size_t)q * NCAND;
  const int*   ci = cand_i + (size_t)q * NCAND;

  float d[SLOTS]; int idx[SLOTS];
#pragma unroll
  for (int s = 0; s < SLOTS; ++s) {
    d[s]   = q2 + ce[lane + 64 * s];    // full d2; merge order matches ref
    idx[s] = ci[lane + 64 * s];
  }

  for (int r = 0; r < KSEL; ++r) {
    float bd = INFINITY; int bi = 0x7fffffff;
#pragma unroll
    for (int s = 0; s < SLOTS; ++s) {
      bool better = (d[s] < bd) || (d[s] == bd && idx[s] < bi);
      if (better) { bd = d[s]; bi = idx[s]; }
    }
#pragma unroll
    for (int off = 32; off; off >>= 1) {
      float od = __shfl_xor(bd, off, 64);
      int   oi = __shfl_xor(bi, off, 64);
      if (od < bd || (od == bd && oi < bi)) { bd = od; bi = oi; }
    }
#pragma unroll
    for (int s = 0; s < SLOTS; ++s)
      if (idx[s] == bi) { d[s] = INFINITY; idx[s] = 0x7fffffff; }
    if (lane == 0) { wd[r] = bd; wi[r] = bi; }
  }
  __syncthreads();

  float sim = 0.f;
  if (lane < KSEL) {
    const float dist = sqrtf(fmaxf(wd[lane], 1e-12f));
    sim = 1.f / (dist + 1e-6f);
  }
  float tot = sim;
#pragma unroll
  for (int off = 8; off; off >>= 1) tot += __shfl_xor(tot, off, 64);
  if (lane < KSEL) {
    out[(size_t)q * KSEL + lane] = (float)wi[lane];
    out[(size_t)NQ * KSEL + (size_t)q * KSEL + lane] = sim / tot;
  }
}

extern "C" void kernel_launch(void* const* d_in, const int* in_sizes, int n_in,
                              void* d_out, int out_size, void* d_ws, size_t ws_size,
                              hipStream_t stream) {
  const float* query   = (const float*)d_in[0];
  const float* support = (const float*)d_in[1];
  float* out = (float*)d_out;

  float* q2     = (float*)d_ws;
  float* s2     = q2 + NQ;
  float* cand_e = s2 + NS;

  constexpr int NCHUNK = 32;
  const size_t need2 = (size_t)(NQ + NS + 2 * NQ * NCHUNK * 2 * KSEL) * 4;  // ~17 MB

  knn_norms<<<(NQ + NS) / 4, 256, 0, stream>>>(query, support, q2, s2);

  if (ws_size >= need2) {
    int* cand_i = (int*)(cand_e + (size_t)NQ * NCHUNK * 2 * KSEL);
    dim3 g1(NQ / 128, NCHUNK);
    knn_phase1<NCHUNK, 2><<<g1, 256, 0, stream>>>(query, support, s2, cand_e, cand_i);
    knn_phase2<NCHUNK * 2 * KSEL><<<NQ, 64, 0, stream>>>(cand_e, cand_i, q2, out);
  } else {
    int* cand_i = (int*)(cand_e + (size_t)NQ * NCHUNK * KSEL);
    dim3 g1(NQ / 128, NCHUNK);
    knn_phase1<NCHUNK, 1><<<g1, 256, 0, stream>>>(query, support, s2, cand_e, cand_i);
    knn_phase2<NCHUNK * KSEL><<<NQ, 64, 0, stream>>>(cand_e, cand_i, q2, out);
  }
}